// Round 7
// baseline (209.235 us; speedup 1.0000x reference)
//
#include <hip/hip_runtime.h>
#include <hip/hip_bf16.h>
#include <math.h>

#define BATCH 8
#define CI    256
#define HWSZ  1600
#define DDIM  128
#define NHEAD 8
#define DH    16
#define NPTS  32768

typedef __attribute__((ext_vector_type(4))) short s16x4;
typedef __attribute__((ext_vector_type(4))) float f32x4;

#if defined(__HIP_DEVICE_COMPILE__)
  #if __has_builtin(__builtin_amdgcn_mfma_f32_16x16x16bf16_1k)
    #define MFMA16(a, b, c) __builtin_amdgcn_mfma_f32_16x16x16bf16_1k(a, b, c, 0, 0, 0)
  #elif __has_builtin(__builtin_amdgcn_mfma_f32_16x16x16_bf16)
    #define MFMA16(a, b, c) __builtin_amdgcn_mfma_f32_16x16x16_bf16(a, b, c, 0, 0, 0)
  #else
    #error "no 16x16x16 bf16 mfma builtin on this device target"
  #endif
#else
  #define MFMA16(a, b, c) (c)
#endif

union fragu {
  s16x4 s;
  unsigned int u[2];
  uint2 u2;
};

// R4/R5-proven RNE packed f32->bf16x2 (R6's inline-asm v_cvt_pk_bf16_f32
// produced NaNs on gfx950 -- semantics differ from assumption; do NOT
// reintroduce without an isolated probe).
__device__ __forceinline__ unsigned int pk_bf2(float a, float b) {
  __hip_bfloat162 h = __float22bfloat162_rn(make_float2(a, b));
  return *(unsigned int*)&h;
}

__device__ __forceinline__ float exp2a(float x) {
#if defined(__HIP_DEVICE_COMPILE__)
  #if __has_builtin(__builtin_amdgcn_exp2f)
  return __builtin_amdgcn_exp2f(x);
  #else
  return exp2f(x);
  #endif
#else
  return x;
#endif
}

__device__ __forceinline__ float bf2f(unsigned short u) {
  return __uint_as_float(((unsigned int)u) << 16);
}

// ---------------- KPREP: blocks 0..63 weight gather; 64..319 cloud -------
// Cloud: ONE ROW PER WAVE -> bid is wave-uniform -> GeM bins live in
// REGISTERS (uniform switch), zero LDS atomics (R5's ga[bid*128+d] atomics
// were 32-way bank-conflicted: stride 128 floats == bank 0 for all lanes).
__global__ __launch_bounds__(256) void kprep(
    const float* __restrict__ W1, const float* __restrict__ W2,
    const float* __restrict__ cf, const int* __restrict__ bids,
    unsigned short* __restrict__ W1s, unsigned short* __restrict__ W2s,
    float* __restrict__ cloud_out, float* __restrict__ gaw,
    float* __restrict__ cntw) {
  int t = threadIdx.x;
  if (blockIdx.x < 64) {
    int e = blockIdx.x * 256 + t;             // 16384 entries
    int lane = e & 63, lm = lane & 15, qd = lane >> 4;
    if (e < 8192) {
      int ks = (e >> 6) & 15, dt = e >> 10;
      const float* p = W1 + (size_t)(ks * 16 + 4 * qd) * DDIM + dt * 16 + lm;
      float f0 = p[0], f1 = p[DDIM], f2 = p[2 * DDIM], f3 = p[3 * DDIM];
      *(uint2*)&W1s[(size_t)e * 4] = make_uint2(pk_bf2(f0, f1), pk_bf2(f2, f3));
    } else {
      int e2 = e - 8192;
      int ks = (e2 >> 6) & 7, ct = e2 >> 9;
      const float* p = W2 + (size_t)(ks * 16 + 4 * qd) * CI + ct * 16 + lm;
      float f0 = p[0], f1 = p[CI], f2 = p[2 * CI], f3 = p[3 * CI];
      *(uint2*)&W2s[(size_t)e2 * 4] = make_uint2(pk_bf2(f0, f1), pk_bf2(f2, f3));
    }
    return;
  }
  __shared__ float ga[4][BATCH * DDIM];       // 16 KB
  __shared__ int gcnt[4][BATCH];
  int bk = blockIdx.x - 64;                   // 0..255
  int w = t >> 6, lane = t & 63;
  int r0 = (bk * 4 + w) * 32;
  float a0x = 0.f, a0y = 0.f, a1x = 0.f, a1y = 0.f;
  float a2x = 0.f, a2y = 0.f, a3x = 0.f, a3y = 0.f;
  float a4x = 0.f, a4y = 0.f, a5x = 0.f, a5y = 0.f;
  float a6x = 0.f, a6y = 0.f, a7x = 0.f, a7y = 0.f;
  int c0 = 0, c1 = 0, c2 = 0, c3 = 0, c4 = 0, c5 = 0, c6 = 0, c7 = 0;
  for (int i = 0; i < 32; i++) {
    int r = r0 + i;
    float2 v = *(const float2*)(cf + (size_t)r * DDIM + lane * 2);
    float ss = v.x * v.x + v.y * v.y;
    ss += __shfl_xor(ss, 1);  ss += __shfl_xor(ss, 2);  ss += __shfl_xor(ss, 4);
    ss += __shfl_xor(ss, 8);  ss += __shfl_xor(ss, 16); ss += __shfl_xor(ss, 32);
    float sc = 1.f / fmaxf(sqrtf(ss), 1e-12f);
    float y0 = v.x * sc, y1 = v.y * sc;
    *(float2*)(cloud_out + (size_t)r * DDIM + lane * 2) = make_float2(y0, y1);
    float p0 = fmaxf(y0, 1e-6f), p1 = fmaxf(y1, 1e-6f);
    p0 = p0 * p0 * p0;
    p1 = p1 * p1 * p1;
    switch (bids[r]) {
      case 0: a0x += p0; a0y += p1; c0++; break;
      case 1: a1x += p0; a1y += p1; c1++; break;
      case 2: a2x += p0; a2y += p1; c2++; break;
      case 3: a3x += p0; a3y += p1; c3++; break;
      case 4: a4x += p0; a4y += p1; c4++; break;
      case 5: a5x += p0; a5y += p1; c5++; break;
      case 6: a6x += p0; a6y += p1; c6++; break;
      default: a7x += p0; a7y += p1; c7++; break;
    }
  }
  float* gw = &ga[w][0];
  *(float2*)&gw[0 * DDIM + 2 * lane] = make_float2(a0x, a0y);
  *(float2*)&gw[1 * DDIM + 2 * lane] = make_float2(a1x, a1y);
  *(float2*)&gw[2 * DDIM + 2 * lane] = make_float2(a2x, a2y);
  *(float2*)&gw[3 * DDIM + 2 * lane] = make_float2(a3x, a3y);
  *(float2*)&gw[4 * DDIM + 2 * lane] = make_float2(a4x, a4y);
  *(float2*)&gw[5 * DDIM + 2 * lane] = make_float2(a5x, a5y);
  *(float2*)&gw[6 * DDIM + 2 * lane] = make_float2(a6x, a6y);
  *(float2*)&gw[7 * DDIM + 2 * lane] = make_float2(a7x, a7y);
  if (lane == 0) {
    gcnt[w][0] = c0; gcnt[w][1] = c1; gcnt[w][2] = c2; gcnt[w][3] = c3;
    gcnt[w][4] = c4; gcnt[w][5] = c5; gcnt[w][6] = c6; gcnt[w][7] = c7;
  }
  __syncthreads();
  for (int j = t; j < BATCH * DDIM; j += 256)
    gaw[(size_t)bk * 1024 + j] = ga[0][j] + ga[1][j] + ga[2][j] + ga[3][j];
  if (t < BATCH)
    cntw[bk * 8 + t] = (float)(gcnt[0][t] + gcnt[1][t] + gcnt[2][t] + gcnt[3][t]);
}

// ---------------- K1: MFMA linear1 + l2norm -> tokh bf16 [B,8,1600,16] ---
__global__ __launch_bounds__(256) void k1_mfma(
    const float* __restrict__ img, const unsigned short* __restrict__ W1s,
    const float* __restrict__ b1, unsigned short* __restrict__ tokh) {
  int t = threadIdx.x, lane = t & 63, w = t >> 6;
  int lm = lane & 15, qd = lane >> 4;
  int blk = blockIdx.x;                      // 200 = 8b x 25 strips of 64
  int b = blk / 25, n0 = (blk % 25) * 64;
  int tok = n0 + w * 16 + lm;
  const float* imgb = img + (size_t)b * CI * HWSZ;
  const s16x4* W1s4 = (const s16x4*)W1s;
  float fv[16][4];
#pragma unroll
  for (int ks = 0; ks < 16; ks++) {
    const float* p = imgb + (size_t)(ks * 16 + 4 * qd) * HWSZ + tok;
    fv[ks][0] = p[0];        fv[ks][1] = p[HWSZ];
    fv[ks][2] = p[2 * HWSZ]; fv[ks][3] = p[3 * HWSZ];
  }
  f32x4 acc[8];
#pragma unroll
  for (int dt = 0; dt < 8; dt++) acc[dt] = (f32x4){0.f, 0.f, 0.f, 0.f};
#pragma unroll
  for (int ks = 0; ks < 16; ks++) {
    fragu bf_;
    bf_.u[0] = pk_bf2(fv[ks][0], fv[ks][1]);
    bf_.u[1] = pk_bf2(fv[ks][2], fv[ks][3]);
#pragma unroll
    for (int dt = 0; dt < 8; dt++) {
      s16x4 af = W1s4[(dt * 16 + ks) * 64 + lane];
      acc[dt] = MFMA16(af, bf_.s, acc[dt]);
    }
  }
  float vals[8][4];
  float ss = 0.f;
#pragma unroll
  for (int dt = 0; dt < 8; dt++)
#pragma unroll
    for (int r = 0; r < 4; r++) {
      float v = acc[dt][r] + b1[dt * 16 + 4 * qd + r];
      vals[dt][r] = v;
      ss += v * v;
    }
  ss += __shfl_xor(ss, 16);
  ss += __shfl_xor(ss, 32);
  float inv = 1.f / fmaxf(sqrtf(ss), 1e-12f);
#pragma unroll
  for (int dt = 0; dt < 8; dt++) {
    uint2 pk = make_uint2(pk_bf2(vals[dt][0] * inv, vals[dt][1] * inv),
                          pk_bf2(vals[dt][2] * inv, vals[dt][3] * inv));
    *(uint2*)&tokh[(((size_t)b * NHEAD + dt) * HWSZ + tok) * DH + 4 * qd] = pk;
  }
}

// ---------------- K2: MFMA flash attention, key-split 2x -----------------
// grid (128,13) x 128 thr: x = bh*2 + kc (800 keys each), y = 128-q strip.
// Single LDS buffer sXk (19.2 KB): K-frags read as b64 rows, V^T-frags
// read as 4 scalar u16 column picks (no sVt, no scalar staging writes).
// Writes unnormalized (num, den) partials; k3 combines.
#define NKC      400
#define XK_STR   24
__global__ __launch_bounds__(128) void k2_attn(
    const unsigned short* __restrict__ tokh, float* __restrict__ numw,
    float* __restrict__ denw) {
  __shared__ unsigned short sXk[NKC * XK_STR];   // 19200 B
  const int gx = blockIdx.x;
  const int bh = gx >> 1, kc = gx & 1;
  const int t = threadIdx.x;
  const int lane = t & 63;
  const int w = t >> 6;
  const int lm = lane & 15;
  const int qd = lane >> 4;
  const unsigned short* tok = tokh + (size_t)bh * (HWSZ * DH);
  const int qw = blockIdx.y * 128 + w * 64;
  const bool active = qw < HWSZ;

  const float SCL = 0.25f * 1.44269504088896f;
  s16x4 qf[4];
  f32x4 oacc[4];
  float den[4];
  if (active) {
#pragma unroll
    for (int s = 0; s < 4; s++) {
      const unsigned short* qs = tok + (size_t)(qw + s * 16 + lm) * DH + 4 * qd;
      s16x4 raw = *(const s16x4*)qs;
      fragu q;
      q.u[0] = pk_bf2(bf2f((unsigned short)raw[0]) * SCL,
                      bf2f((unsigned short)raw[1]) * SCL);
      q.u[1] = pk_bf2(bf2f((unsigned short)raw[2]) * SCL,
                      bf2f((unsigned short)raw[3]) * SCL);
      qf[s] = q.s;
      oacc[s] = (f32x4){0.f, 0.f, 0.f, 0.f};
      den[s] = 0.f;
    }
  }

  for (int cc = 0; cc < 2; cc++) {
    int c = kc * 2 + cc;
    __syncthreads();
    for (int i = t; i < 2 * NKC; i += 128) {
      int r = i >> 1, hf = i & 1;
      *(uint4*)&sXk[r * XK_STR + hf * 8] =
          *(const uint4*)(tok + (size_t)(c * NKC + r) * DH + hf * 8);
    }
    __syncthreads();
    if (active) {
#pragma unroll 1
      for (int st = 0; st < NKC / 16; st++) {
        int n0 = st * 16;
        s16x4 kf = *(const s16x4*)&sXk[(n0 + lm) * XK_STR + 4 * qd];
        const unsigned short* vb = &sXk[(n0 + 4 * qd) * XK_STR + lm];
        fragu vv;
        vv.u[0] = (unsigned int)vb[0] | ((unsigned int)vb[XK_STR] << 16);
        vv.u[1] = (unsigned int)vb[2 * XK_STR] | ((unsigned int)vb[3 * XK_STR] << 16);
        f32x4 sc[4];
#pragma unroll
        for (int s = 0; s < 4; s++)
          sc[s] = MFMA16(kf, qf[s], ((f32x4){0.f, 0.f, 0.f, 0.f}));
        fragu pf[4];
#pragma unroll
        for (int s = 0; s < 4; s++) {
          float e0 = exp2a(sc[s].x), e1 = exp2a(sc[s].y);
          float e2 = exp2a(sc[s].z), e3 = exp2a(sc[s].w);
          den[s] += (e0 + e1) + (e2 + e3);
          pf[s].u[0] = pk_bf2(e0, e1);
          pf[s].u[1] = pk_bf2(e2, e3);
        }
#pragma unroll
        for (int s = 0; s < 4; s++)
          oacc[s] = MFMA16(vv.s, pf[s].s, oacc[s]);
      }
    }
  }

  if (active) {
#pragma unroll
    for (int s = 0; s < 4; s++) {
      float d = den[s];
      d += __shfl_xor(d, 16);
      d += __shfl_xor(d, 32);
      size_t q = (size_t)qw + s * 16 + lm;
      float* np = numw + (((size_t)bh * 2 + kc) * HWSZ + q) * 16 + 4 * qd;
      *(f32x4*)np = oacc[s];
      if (qd == 0) denw[((size_t)bh * 2 + kc) * HWSZ + q] = d;
    }
  }
}

// ---------------- K3: combine attn partials + MFMA linear2 ---------------
__global__ __launch_bounds__(256) void k3_mfma(
    const float* __restrict__ numw, const float* __restrict__ denw,
    const unsigned short* __restrict__ W2s, const float* __restrict__ b2,
    float* __restrict__ img_out) {
  int t = threadIdx.x, lane = t & 63, w = t >> 6;
  int lm = lane & 15, qd = lane >> 4;
  int blk = blockIdx.x;                      // 200 = 8b x 25 strips of 64
  int b = blk / 25, n0 = (blk % 25) * 64;
  int tok = n0 + w * 16 + lm;
  const s16x4* W2s4 = (const s16x4*)W2s;
  f32x4 acc[16];
#pragma unroll
  for (int ct = 0; ct < 16; ct++) acc[ct] = (f32x4){0.f, 0.f, 0.f, 0.f};
#pragma unroll 2
  for (int ks = 0; ks < 8; ks++) {
    size_t bh2 = (size_t)(b * 8 + ks) * 2;
    const float* npb = numw + (bh2 * HWSZ + tok) * 16 + 4 * qd;
    f32x4 nv0 = *(const f32x4*)npb;
    f32x4 nv1 = *(const f32x4*)(npb + (size_t)HWSZ * 16);
    float d0 = denw[bh2 * HWSZ + tok];
    float d1 = denw[bh2 * HWSZ + HWSZ + tok];
    float inv = 1.f / (d0 + d1);
    fragu bf_;
    bf_.u[0] = pk_bf2((nv0.x + nv1.x) * inv, (nv0.y + nv1.y) * inv);
    bf_.u[1] = pk_bf2((nv0.z + nv1.z) * inv, (nv0.w + nv1.w) * inv);
#pragma unroll
    for (int ct = 0; ct < 16; ct++) {
      s16x4 af = W2s4[(ct * 8 + ks) * 64 + lane];
      acc[ct] = MFMA16(af, bf_.s, acc[ct]);
    }
  }
  float* ob = img_out + (size_t)b * CI * HWSZ;
#pragma unroll
  for (int ct = 0; ct < 16; ct++)
#pragma unroll
    for (int r = 0; r < 4; r++) {
      int ci = ct * 16 + 4 * qd + r;
      ob[(size_t)ci * HWSZ + tok] = acc[ct][r] + b2[ci];
    }
}

// ---------------- KPOST: image GeM rows + cloud GeM combine --------------
__global__ __launch_bounds__(256) void kpost(
    const float* __restrict__ img_out, const float* __restrict__ gaw,
    const float* __restrict__ cntw, float* __restrict__ image_gem,
    float* __restrict__ cloud_gem) {
  __shared__ float cs[BATCH];
  int t = threadIdx.x;
  if (blockIdx.x < 512) {
    int w = t >> 6, lane = t & 63;
    int row = blockIdx.x * 4 + w;            // 2048 rows of 1600
    const float* r = img_out + (size_t)row * HWSZ;
    float s = 0.f;
    for (int i = lane; i < HWSZ; i += 64) {
      float c = fmaxf(r[i], 1e-6f);
      s += c * c * c;
    }
    s += __shfl_xor(s, 1);  s += __shfl_xor(s, 2);  s += __shfl_xor(s, 4);
    s += __shfl_xor(s, 8);  s += __shfl_xor(s, 16); s += __shfl_xor(s, 32);
    if (lane == 0) image_gem[row] = powf(s * (1.f / (float)HWSZ), 1.f / 3.f);
  } else {
    int j = (blockIdx.x - 512) * 256 + t;    // 0..1023
    if (t < BATCH) {
      float s = 0.f;
      for (int k = 0; k < 256; k++) s += cntw[k * 8 + t];
      cs[t] = s;
    }
    __syncthreads();
    float s = 0.f;
#pragma unroll 4
    for (int k = 0; k < 256; k++) s += gaw[(size_t)k * 1024 + j];
    int b = j >> 7;
    cloud_gem[j] = powf(s / fmaxf(cs[b], 1.f), 1.f / 3.f);
  }
}

extern "C" void kernel_launch(void* const* d_in, const int* in_sizes, int n_in,
                              void* d_out, int out_size, void* d_ws, size_t ws_size,
                              hipStream_t stream) {
  const float* image_feat = (const float*)d_in[0];
  const float* cloud_feat = (const float*)d_in[1];
  const int*   cloud_bids = (const int*)d_in[2];
  const float* W1 = (const float*)d_in[3];
  const float* b1 = (const float*)d_in[4];
  const float* W2 = (const float*)d_in[5];
  const float* b2 = (const float*)d_in[6];

  float* out = (float*)d_out;
  float* img_out   = out;                                  // [8,256,40,40]
  float* cloud_out = out + 3276800;                        // [32768,128]
  float* image_gem = out + 3276800 + 4194304;              // [8,256]
  float* cloud_gem = image_gem + 2048;                     // [8,128]

  char* ws = (char*)d_ws;
  unsigned short* tokh = (unsigned short*)ws;              // 3,276,800 B
  float* numw = (float*)(ws + 3276800);                    // 13,107,200 B
  float* denw = (float*)(ws + 16384000);                   //    819,200 B
  unsigned short* W1s = (unsigned short*)(ws + 17203200);  //     65,536 B
  unsigned short* W2s = (unsigned short*)(ws + 17268736);  //     65,536 B
  float* gaw  = (float*)(ws + 17334272);                   //  1,048,576 B
  float* cntw = (float*)(ws + 18382848);                   //      8,192 B

  kprep<<<dim3(320), dim3(256), 0, stream>>>(W1, W2, cloud_feat, cloud_bids,
                                             W1s, W2s, cloud_out, gaw, cntw);
  k1_mfma<<<dim3(200), dim3(256), 0, stream>>>(image_feat, W1s, b1, tokh);
  k2_attn<<<dim3(128, 13), dim3(128), 0, stream>>>(tokh, numw, denw);
  k3_mfma<<<dim3(200), dim3(256), 0, stream>>>(numw, denw, W2s, b2, img_out);
  kpost<<<dim3(516), dim3(256), 0, stream>>>(img_out, gaw, cntw,
                                             image_gem, cloud_gem);
}